// Round 14
// baseline (7770.261 us; speedup 1.0000x reference)
//
#include <hip/hip_runtime.h>

typedef _Float16 f16;
typedef _Float16 f16x8 __attribute__((ext_vector_type(8)));
typedef _Float16 f16x4 __attribute__((ext_vector_type(4)));
typedef float f32x4 __attribute__((ext_vector_type(4)));

#define H_    256
#define TB_   64      // batch rows per workgroup
#define NT_   1024    // 16 waves, 4 per SIMD, 1 WG/CU
#define SORB_ 64
#define SLOT_ 8192    // 32 rows * 256 cols f16 = 16 KB; one h buffer = 2 slots (64 rows)

#define MFMA16(a, b, c) __builtin_amdgcn_mfma_f32_16x16x32_f16((a), (b), (c), 0, 0, 0)
#define UNR _Pragma("unroll")

__device__ __forceinline__ float sigm(float v) {
  return __builtin_amdgcn_rcpf(1.0f + __builtin_amdgcn_exp2f(v * -1.442695040888963f));
}
__device__ __forceinline__ float tanh_fast(float v) {
  float a = fabsf(v);
  float e = __builtin_amdgcn_exp2f(a * -2.885390081777927f);
  float t = (1.0f - e) * __builtin_amdgcn_rcpf(1.0f + e);
  return copysignf(t, v);
}
// XOR-swizzle; (lrow^(lrow>>2))&7 separates all four lg groups in the scalar
// epilogue (2-way instead of 4-way bank conflicts); A-read pairs stay 2-way.
__device__ __forceinline__ int lswz(int lrow, int col) {
  return lrow * H_ + (col ^ (((lrow ^ (lrow >> 2)) & 7) << 3));
}

// fp32 -> f16 weight conversion: [whh0 | wih1 | whh1], each [768][256] row-major
__global__ void wcvt(const float* __restrict__ a, const float* __restrict__ b,
                     const float* __restrict__ c, f16* __restrict__ o) {
  int i = blockIdx.x * 256 + threadIdx.x;
  const int n = 768 * 256;
  if (i < n) {
    o[i]         = (f16)a[i];
    o[n + i]     = (f16)b[i];
    o[2 * n + i] = (f16)c[i];
  }
}

// Register model (R12/R13 A/B): allocator fixes 64 arch + 64 accum regardless of
// launch_bounds / waves_per_eu. So the kernel must keep ARCH live-set < 64 at every
// point: no f32 arrays live across MFMA regions (T runs per-m-chunk, all 4 gate
// accumulators in one kt loop, purely element-wise epilogue).
__global__ __attribute__((amdgpu_flat_work_group_size(NT_, NT_), amdgpu_waves_per_eu(4, 4)))
void rnnwf(
    const int* __restrict__ x,
    const float* __restrict__ w_ih0, const float* __restrict__ b_ih0,
    const float* __restrict__ b_hh0, const float* __restrict__ b_ih1,
    const float* __restrict__ b_hh1, const float* __restrict__ w_amp,
    const float* __restrict__ b_amp, const f16* __restrict__ W16,
    float* __restrict__ out)
{
  // h0 ping-pong (2x2 slots) + h1 ping-pong (2x2 slots) = 128 KB
  __shared__ __align__(16) f16 hall[8 * SLOT_];
  __shared__ float wampL[512];
  __shared__ __align__(8) unsigned short bitsL[TB_ * 4];
  __shared__ unsigned long long bitsT[SORB_];

  const int tid  = threadIdx.x;
  const int wave = tid >> 6;                  // 0..15
  const int lane = tid & 63;
  const int l15  = lane & 15;
  const int lg   = lane >> 4;                 // 0..3
  const int lg4  = lg << 2;
  const int col  = wave * 16 + l15;           // fixed hidden column per thread
  const int rowbase = blockIdx.x * TB_;

  // ---- one-time setup ----
  for (int j = tid; j < 512; j += NT_) wampL[j] = w_amp[j];
  if (tid < TB_ * 4) {
    const int* xp = x + (size_t)(rowbase + (tid >> 2)) * SORB_ + (tid & 3) * 16;
    unsigned m = 0;
    #pragma unroll
    for (int i = 0; i < 16; ++i) m |= (unsigned)(xp[i] & 1) << i;
    bitsL[tid] = (unsigned short)m;
  }
  for (int i = tid; i < 8 * SLOT_; i += NT_) hall[i] = (f16)0.f;
  __syncthreads();
  if (tid < SORB_) {                 // bitsT[t]: bit r = x[row r][t]
    unsigned long long mkk = 0ull;
    const int q = tid >> 4, sh = tid & 15;
    #pragma unroll 4
    for (int r = 0; r < TB_; ++r)
      mkk |= (unsigned long long)((bitsL[r * 4 + q] >> sh) & 1) << r;
    bitsT[tid] = mkk;
  }
  const int hrow = tid >> 4;                  // head: 64 rows, 16 threads each
  const int t16  = tid & 15;
  const unsigned long long hmk = ((const unsigned long long*)bitsL)[hrow];

  // per-thread constants
  const float baseR = b_ih0[col]       + b_hh0[col];
  const float baseZ = b_ih0[256 + col] + b_hh0[256 + col];
  const float baseN = b_ih0[512 + col];
  const float sumR0 = baseR + w_ih0[2 * col + 0],         dR = w_ih0[2 * col + 1] - w_ih0[2 * col + 0];
  const float sumZ0 = baseZ + w_ih0[2 * (256 + col) + 0], dZ = w_ih0[2 * (256 + col) + 1] - w_ih0[2 * (256 + col) + 0];
  const float sumN0 = baseN + w_ih0[2 * (512 + col) + 0], dN = w_ih0[2 * (512 + col) + 1] - w_ih0[2 * (512 + col) + 0];
  const float bhh0n_c = b_hh0[512 + col];
  const float b1r_c   = b_ih1[col]       + b_hh1[col];
  const float b1z_c   = b_ih1[256 + col] + b_hh1[256 + col];
  const float b1ni_c  = b_ih1[512 + col];
  const float b1nh_c  = b_hh1[512 + col];
  const float ba0 = b_amp[0], ba1 = b_amp[1];
  __syncthreads();

  float prob = 1.0f;
  const f16* p0base = W16 + col * 256;
  const f16* pibase = W16 + 768 * 256 + col * 256;
  const f16* phbase = W16 + 2 * 768 * 256 + col * 256;

  // previous-step h at this thread's own (lrow,col) D-fragment positions
  f16x4 h0p[4], h1p[4];
  UNR for (int m = 0; m < 4; ++m) { h0p[m] = (f16x4){0,0,0,0}; h1p[m] = h0p[m]; }

  // Pipelined schedule (one barrier/iter): iter tau computes T = L1(tau-1) [tau>=0]
  // then S = L0(tau) [tau<64], head(tau-2) [tau>=2]. h ping-pong read (tau+1)&1, write tau&1.
  for (int tau = -1; tau <= 64; ++tau) {
    const int h0r = ((tau + 1) & 1) * (2 * SLOT_);
    const int h0w = (tau & 1) * (2 * SLOT_);
    const int h1r = 4 * SLOT_ + ((tau + 1) & 1) * (2 * SLOT_);
    const int h1w = 4 * SLOT_ + (tau & 1) * (2 * SLOT_);

    unsigned lo32 = 0u, hi32 = 0u;
    if (tau >= 0 && tau < 64) {
      unsigned long long mkk = bitsT[tau];     // uniform -> broadcast
      lo32 = (unsigned)mkk; hi32 = (unsigned)(mkk >> 32);
    }

    // ===== T = L1(tau-1): two m-chunks, all 4 gate accs in ONE kt loop =====
    // (accumulation order per gate identical to the split version: kt ascending,
    //  A0 before A1 -> bitwise-identical results; no f32 arrays live across loops)
    if (tau >= 0) {
      UNR for (int mc = 0; mc < 2; ++mc) {    // chunk mc covers gm = 2*mc, 2*mc+1
        f32x4 tR[2], tZ[2], tNi[2], tNh[2];
        UNR for (int m = 0; m < 2; ++m) {
          tR[m] = (f32x4){0,0,0,0}; tZ[m] = tR[m]; tNi[m] = tR[m]; tNh[m] = tR[m];
        }
        #pragma unroll 2
        for (int kt = 0; kt < 8; ++kt) {
          const int k0 = kt * 32 + lg * 8;
          f16x8 BiR = *(const f16x8*)(pibase + k0);
          f16x8 BiZ = *(const f16x8*)(pibase + 65536 + k0);
          f16x8 BiN = *(const f16x8*)(pibase + 131072 + k0);
          f16x8 BhR = *(const f16x8*)(phbase + k0);
          f16x8 BhZ = *(const f16x8*)(phbase + 65536 + k0);
          f16x8 BhN = *(const f16x8*)(phbase + 131072 + k0);
          UNR for (int m = 0; m < 2; ++m) {
            const int gm = mc * 2 + m;
            f16x8 A0 = *(const f16x8*)&hall[h0r + (gm >> 1) * SLOT_ + lswz((gm & 1) * 16 + l15, k0)];
            f16x8 A1 = *(const f16x8*)&hall[h1r + (gm >> 1) * SLOT_ + lswz((gm & 1) * 16 + l15, k0)];
            tR[m]  = MFMA16(A0, BiR, tR[m]);   tR[m] = MFMA16(A1, BhR, tR[m]);
            tZ[m]  = MFMA16(A0, BiZ, tZ[m]);   tZ[m] = MFMA16(A1, BhZ, tZ[m]);
            tNi[m] = MFMA16(A0, BiN, tNi[m]);
            tNh[m] = MFMA16(A1, BhN, tNh[m]);
          }
        }
        // element-wise epilogue: no cross-element f32 state
        UNR for (int m = 0; m < 2; ++m) {
          const int gm = mc * 2 + m;
          UNR for (int e = 0; e < 4; ++e) {
            const int lrow = (gm & 1) * 16 + lg4 + e;
            float r  = sigm(tR[m][e] + b1r_c);
            float z  = sigm(tZ[m][e] + b1z_c);
            float n  = tanh_fast(tNi[m][e] + b1ni_c + r * (tNh[m][e] + b1nh_c));
            float hn = (1.0f - z) * n + z * (float)h1p[gm][e];
            h1p[gm][e] = (f16)hn;
            hall[h1w + (gm >> 1) * SLOT_ + lswz(lrow, col)] = h1p[gm][e];
          }
        }
      }
    }

    // ================= S = L0(tau) =================
    if (tau < 64) {
      f32x4 aR[4], aZ[4], aN[4];
      UNR for (int m = 0; m < 4; ++m) { aR[m] = (f32x4){0,0,0,0}; aZ[m] = aR[m]; aN[m] = aR[m]; }
      #pragma unroll 2
      for (int kt = 0; kt < 8; ++kt) {
        const int k0 = kt * 32 + lg * 8;
        f16x8 Br = *(const f16x8*)(p0base + k0);
        f16x8 Bz = *(const f16x8*)(p0base + 65536 + k0);
        f16x8 Bn = *(const f16x8*)(p0base + 131072 + k0);
        UNR for (int m = 0; m < 4; ++m) {
          f16x8 A = *(const f16x8*)&hall[h0r + (m >> 1) * SLOT_ + lswz((m & 1) * 16 + l15, k0)];
          aR[m] = MFMA16(A, Br, aR[m]);
          aZ[m] = MFMA16(A, Bz, aZ[m]);
          aN[m] = MFMA16(A, Bn, aN[m]);
        }
      }
      if (tau >= 0) {
        UNR for (int m = 0; m < 4; ++m) {
          const unsigned hsel = (m < 2) ? lo32 : hi32;
          UNR for (int e = 0; e < 4; ++e) {
            const int lrow = (m & 1) * 16 + lg4 + e;
            float fb = (float)((hsel >> ((m & 1) * 16 + lg4 + e)) & 1u);
            float giR = fmaf(fb, dR, sumR0);
            float giZ = fmaf(fb, dZ, sumZ0);
            float giN = fmaf(fb, dN, sumN0);
            float r  = sigm(aR[m][e] + giR);
            float z  = sigm(aZ[m][e] + giZ);
            float n  = tanh_fast(giN + r * (aN[m][e] + bhh0n_c));
            float hn = (1.0f - z) * n + z * (float)h0p[m][e];
            h0p[m][e] = (f16)hn;
            hall[h0w + (m >> 1) * SLOT_ + lswz(lrow, col)] = h0p[m][e];
          }
        }
      } else {
        UNR for (int m = 0; m < 4; ++m) {
          UNR for (int e = 0; e < 4; ++e) {
            const int lrow = (m & 1) * 16 + lg4 + e;
            float r  = sigm(aR[m][e] + baseR);
            float z  = sigm(aZ[m][e] + baseZ);
            float n  = tanh_fast(baseN + r * (aN[m][e] + bhh0n_c));
            float hn = (1.0f - z) * n;           // h0_old = 0
            h0p[m][e] = (f16)hn;
            hall[h0w + (m >> 1) * SLOT_ + lswz(lrow, col)] = h0p[m][e];
          }
        }
      }
    }

    // ================= head(tau-2): reads h1'(tau-2) in h1r =================
    if (tau >= 2) {
      const int t = tau - 2;
      float d0 = 0.f, d1 = 0.f;
      #pragma unroll
      for (int j = 0; j < 2; ++j) {
        const int k0 = t16 * 16 + j * 8;
        f16x8 hv = *(const f16x8*)&hall[h1r + (hrow >> 5) * SLOT_ + lswz(hrow & 31, k0)];
        f32x4 w0a = *(const f32x4*)&wampL[k0];
        f32x4 w0b = *(const f32x4*)&wampL[k0 + 4];
        f32x4 w1a = *(const f32x4*)&wampL[256 + k0];
        f32x4 w1b = *(const f32x4*)&wampL[256 + k0 + 4];
        #pragma unroll
        for (int i = 0; i < 4; ++i) {
          float hfa = (float)hv[i], hfb = (float)hv[4 + i];
          d0 = fmaf(hfa, w0a[i], d0); d0 = fmaf(hfb, w0b[i], d0);
          d1 = fmaf(hfa, w1a[i], d1); d1 = fmaf(hfb, w1b[i], d1);
        }
      }
      d0 += __shfl_xor(d0, 1); d0 += __shfl_xor(d0, 2);
      d0 += __shfl_xor(d0, 4); d0 += __shfl_xor(d0, 8);
      d1 += __shfl_xor(d1, 1); d1 += __shfl_xor(d1, 2);
      d1 += __shfl_xor(d1, 4); d1 += __shfl_xor(d1, 8);
      const int bit = (unsigned)(hmk >> t) & 1u;
      float diff = (d0 + ba0) - (d1 + ba1);
      if (bit) diff = -diff;
      prob *= __builtin_amdgcn_rcpf(1.0f + __builtin_amdgcn_exp2f(diff * -1.442695040888963f));
    }
    __syncthreads();
  }

  // final head: t = 63; h1'(63) written at iter 64 to slot (64&1)=0
  {
    const int hb = 4 * SLOT_;
    float d0 = 0.f, d1 = 0.f;
    #pragma unroll
    for (int j = 0; j < 2; ++j) {
      const int k0 = t16 * 16 + j * 8;
      f16x8 hv = *(const f16x8*)&hall[hb + (hrow >> 5) * SLOT_ + lswz(hrow & 31, k0)];
      f32x4 w0a = *(const f32x4*)&wampL[k0];
      f32x4 w0b = *(const f32x4*)&wampL[k0 + 4];
      f32x4 w1a = *(const f32x4*)&wampL[256 + k0];
      f32x4 w1b = *(const f32x4*)&wampL[256 + k0 + 4];
      #pragma unroll
      for (int i = 0; i < 4; ++i) {
        float hfa = (float)hv[i], hfb = (float)hv[4 + i];
        d0 = fmaf(hfa, w0a[i], d0); d0 = fmaf(hfb, w0b[i], d0);
        d1 = fmaf(hfa, w1a[i], d1); d1 = fmaf(hfb, w1b[i], d1);
      }
    }
    d0 += __shfl_xor(d0, 1); d0 += __shfl_xor(d0, 2);
    d0 += __shfl_xor(d0, 4); d0 += __shfl_xor(d0, 8);
    d1 += __shfl_xor(d1, 1); d1 += __shfl_xor(d1, 2);
    d1 += __shfl_xor(d1, 4); d1 += __shfl_xor(d1, 8);
    const int bit = (unsigned)(hmk >> 63) & 1u;
    float diff = (d0 + ba0) - (d1 + ba1);
    if (bit) diff = -diff;
    prob *= __builtin_amdgcn_rcpf(1.0f + __builtin_amdgcn_exp2f(diff * -1.442695040888963f));
  }

  if (t16 == 0) out[rowbase + hrow] = sqrtf(prob);
}

extern "C" void kernel_launch(void* const* d_in, const int* in_sizes, int n_in,
                              void* d_out, int out_size, void* d_ws, size_t ws_size,
                              hipStream_t stream) {
  const int*   x     = (const int*)d_in[0];
  const float* w_ih0 = (const float*)d_in[1];
  const float* w_hh0 = (const float*)d_in[2];
  const float* b_ih0 = (const float*)d_in[3];
  const float* b_hh0 = (const float*)d_in[4];
  const float* w_ih1 = (const float*)d_in[5];
  const float* w_hh1 = (const float*)d_in[6];
  const float* b_ih1 = (const float*)d_in[7];
  const float* b_hh1 = (const float*)d_in[8];
  const float* w_amp = (const float*)d_in[9];
  const float* b_amp = (const float*)d_in[10];
  (void)in_sizes; (void)n_in; (void)out_size; (void)ws_size;

  f16* W16 = (f16*)d_ws;   // 3*768*256*2 = 1.18 MB of workspace
  hipLaunchKernelGGL(wcvt, dim3(768), dim3(256), 0, stream, w_hh0, w_ih1, w_hh1, W16);
  hipLaunchKernelGGL(rnnwf, dim3(32768 / TB_), dim3(NT_), 0, stream,
                     x, w_ih0, b_ih0, b_hh0, b_ih1, b_hh1, w_amp, b_amp, W16,
                     (float*)d_out);
}

// Round 15
// 5684.697 us; speedup vs baseline: 1.3669x; 1.3669x over previous
//
#include <hip/hip_runtime.h>

typedef _Float16 f16;
typedef _Float16 f16x8 __attribute__((ext_vector_type(8)));
typedef _Float16 f16x4 __attribute__((ext_vector_type(4)));
typedef float f32x4 __attribute__((ext_vector_type(4)));

#define H_    256
#define TB_   64      // batch rows per workgroup
#define NT_   1024    // 16 waves, 4 per SIMD, 1 WG/CU
#define SORB_ 64
#define SLOT_ 8192    // 32 rows * 256 cols f16 = 16 KB; one h buffer = 2 slots (64 rows)

#define MFMA16(a, b, c) __builtin_amdgcn_mfma_f32_16x16x32_f16((a), (b), (c), 0, 0, 0)
#define UNR _Pragma("unroll")

__device__ __forceinline__ float sigm(float v) {
  return __builtin_amdgcn_rcpf(1.0f + __builtin_amdgcn_exp2f(v * -1.442695040888963f));
}
__device__ __forceinline__ float tanh_fast(float v) {
  float a = fabsf(v);
  float e = __builtin_amdgcn_exp2f(a * -2.885390081777927f);
  float t = (1.0f - e) * __builtin_amdgcn_rcpf(1.0f + e);
  return copysignf(t, v);
}
// XOR-swizzle; (lrow^(lrow>>2))&7 separates all four lg groups in the scalar
// epilogue (2-way instead of 4-way bank conflicts); A-read pairs stay 2-way.
__device__ __forceinline__ int lswz(int lrow, int col) {
  return lrow * H_ + (col ^ (((lrow ^ (lrow >> 2)) & 7) << 3));
}

// fp32 -> f16 weight conversion: [whh0 | wih1 | whh1], each [768][256] row-major
__global__ void wcvt(const float* __restrict__ a, const float* __restrict__ b,
                     const float* __restrict__ c, f16* __restrict__ o) {
  int i = blockIdx.x * 256 + threadIdx.x;
  const int n = 768 * 256;
  if (i < n) {
    o[i]         = (f16)a[i];
    o[n + i]     = (f16)b[i];
    o[2 * n + i] = (f16)c[i];
  }
}

// Register model (R12-R14): allocator fixes 64 arch + 64 accum regs. T phase uses
// ALL 64 accum regs (4 gates x 4 m-tiles) in ONE kt loop -- B loaded once per kt,
// A0/A1 each read once per kt, epilogue purely element-wise (nothing to spill).
__global__ __attribute__((amdgpu_flat_work_group_size(NT_, NT_), amdgpu_waves_per_eu(4, 4)))
void rnnwf(
    const int* __restrict__ x,
    const float* __restrict__ w_ih0, const float* __restrict__ b_ih0,
    const float* __restrict__ b_hh0, const float* __restrict__ b_ih1,
    const float* __restrict__ b_hh1, const float* __restrict__ w_amp,
    const float* __restrict__ b_amp, const f16* __restrict__ W16,
    float* __restrict__ out)
{
  // h0 ping-pong (2x2 slots) + h1 ping-pong (2x2 slots) = 128 KB
  __shared__ __align__(16) f16 hall[8 * SLOT_];
  __shared__ float wampL[512];
  __shared__ __align__(8) unsigned short bitsL[TB_ * 4];
  __shared__ unsigned long long bitsT[SORB_];

  const int tid  = threadIdx.x;
  const int wave = tid >> 6;                  // 0..15
  const int lane = tid & 63;
  const int l15  = lane & 15;
  const int lg   = lane >> 4;                 // 0..3
  const int lg4  = lg << 2;
  const int col  = wave * 16 + l15;           // fixed hidden column per thread
  const int rowbase = blockIdx.x * TB_;

  // ---- one-time setup ----
  for (int j = tid; j < 512; j += NT_) wampL[j] = w_amp[j];
  if (tid < TB_ * 4) {
    const int* xp = x + (size_t)(rowbase + (tid >> 2)) * SORB_ + (tid & 3) * 16;
    unsigned m = 0;
    #pragma unroll
    for (int i = 0; i < 16; ++i) m |= (unsigned)(xp[i] & 1) << i;
    bitsL[tid] = (unsigned short)m;
  }
  for (int i = tid; i < 8 * SLOT_; i += NT_) hall[i] = (f16)0.f;
  __syncthreads();
  if (tid < SORB_) {                 // bitsT[t]: bit r = x[row r][t]
    unsigned long long mkk = 0ull;
    const int q = tid >> 4, sh = tid & 15;
    #pragma unroll 4
    for (int r = 0; r < TB_; ++r)
      mkk |= (unsigned long long)((bitsL[r * 4 + q] >> sh) & 1) << r;
    bitsT[tid] = mkk;
  }
  const int hrow = tid >> 4;                  // head: 64 rows, 16 threads each
  const int t16  = tid & 15;
  const unsigned long long hmk = ((const unsigned long long*)bitsL)[hrow];

  // per-thread constants
  const float baseR = b_ih0[col]       + b_hh0[col];
  const float baseZ = b_ih0[256 + col] + b_hh0[256 + col];
  const float baseN = b_ih0[512 + col];
  const float sumR0 = baseR + w_ih0[2 * col + 0],         dR = w_ih0[2 * col + 1] - w_ih0[2 * col + 0];
  const float sumZ0 = baseZ + w_ih0[2 * (256 + col) + 0], dZ = w_ih0[2 * (256 + col) + 1] - w_ih0[2 * (256 + col) + 0];
  const float sumN0 = baseN + w_ih0[2 * (512 + col) + 0], dN = w_ih0[2 * (512 + col) + 1] - w_ih0[2 * (512 + col) + 0];
  const float bhh0n_c = b_hh0[512 + col];
  const float b1r_c   = b_ih1[col]       + b_hh1[col];
  const float b1z_c   = b_ih1[256 + col] + b_hh1[256 + col];
  const float b1ni_c  = b_ih1[512 + col];
  const float b1nh_c  = b_hh1[512 + col];
  const float ba0 = b_amp[0], ba1 = b_amp[1];
  __syncthreads();

  float prob = 1.0f;
  const f16* p0base = W16 + col * 256;
  const f16* pibase = W16 + 768 * 256 + col * 256;
  const f16* phbase = W16 + 2 * 768 * 256 + col * 256;

  // previous-step h at this thread's own (lrow,col) D-fragment positions
  f16x4 h0p[4], h1p[4];
  UNR for (int m = 0; m < 4; ++m) { h0p[m] = (f16x4){0,0,0,0}; h1p[m] = h0p[m]; }

  // Pipelined schedule (one barrier/iter): iter tau computes T = L1(tau-1) [tau>=0]
  // then S = L0(tau) [tau<64], head(tau-2) [tau>=2]. h ping-pong read (tau+1)&1, write tau&1.
  for (int tau = -1; tau <= 64; ++tau) {
    const int h0r = ((tau + 1) & 1) * (2 * SLOT_);
    const int h0w = (tau & 1) * (2 * SLOT_);
    const int h1r = 4 * SLOT_ + ((tau + 1) & 1) * (2 * SLOT_);
    const int h1w = 4 * SLOT_ + (tau & 1) * (2 * SLOT_);

    unsigned lo32 = 0u, hi32 = 0u;
    if (tau >= 0 && tau < 64) {
      unsigned long long mkk = bitsT[tau];     // uniform -> broadcast
      lo32 = (unsigned)mkk; hi32 = (unsigned)(mkk >> 32);
    }

    // ===== T = L1(tau-1): ONE kt loop, 4 m-tiles, 64 accum regs =====
    // Per accumulator: A0-contribution before A1 within each kt, kt ascending --
    // identical accumulation order to the split version (bitwise-same result).
    if (tau >= 0) {
      f32x4 tR[4], tZ[4], tNi[4], tNh[4];
      UNR for (int m = 0; m < 4; ++m) {
        tR[m] = (f32x4){0,0,0,0}; tZ[m] = tR[m]; tNi[m] = tR[m]; tNh[m] = tR[m];
      }
      #pragma unroll 1
      for (int kt = 0; kt < 8; ++kt) {
        const int k0 = kt * 32 + lg * 8;
        {  // ih source: 3 B streams live, A0 loaded per-m
          f16x8 BiR = *(const f16x8*)(pibase + k0);
          f16x8 BiZ = *(const f16x8*)(pibase + 65536 + k0);
          f16x8 BiN = *(const f16x8*)(pibase + 131072 + k0);
          UNR for (int m = 0; m < 4; ++m) {
            f16x8 A0 = *(const f16x8*)&hall[h0r + (m >> 1) * SLOT_ + lswz((m & 1) * 16 + l15, k0)];
            tR[m]  = MFMA16(A0, BiR, tR[m]);
            tZ[m]  = MFMA16(A0, BiZ, tZ[m]);
            tNi[m] = MFMA16(A0, BiN, tNi[m]);
          }
        }
        {  // hh source
          f16x8 BhR = *(const f16x8*)(phbase + k0);
          f16x8 BhZ = *(const f16x8*)(phbase + 65536 + k0);
          f16x8 BhN = *(const f16x8*)(phbase + 131072 + k0);
          UNR for (int m = 0; m < 4; ++m) {
            f16x8 A1 = *(const f16x8*)&hall[h1r + (m >> 1) * SLOT_ + lswz((m & 1) * 16 + l15, k0)];
            tR[m]  = MFMA16(A1, BhR, tR[m]);
            tZ[m]  = MFMA16(A1, BhZ, tZ[m]);
            tNh[m] = MFMA16(A1, BhN, tNh[m]);
          }
        }
      }
      // element-wise epilogue: no cross-element f32 state
      UNR for (int m = 0; m < 4; ++m) {
        UNR for (int e = 0; e < 4; ++e) {
          const int lrow = (m & 1) * 16 + lg4 + e;
          float r  = sigm(tR[m][e] + b1r_c);
          float z  = sigm(tZ[m][e] + b1z_c);
          float n  = tanh_fast(tNi[m][e] + b1ni_c + r * (tNh[m][e] + b1nh_c));
          float hn = (1.0f - z) * n + z * (float)h1p[m][e];
          h1p[m][e] = (f16)hn;
          hall[h1w + (m >> 1) * SLOT_ + lswz(lrow, col)] = h1p[m][e];
        }
      }
    }

    // ================= S = L0(tau) =================
    if (tau < 64) {
      f32x4 aR[4], aZ[4], aN[4];
      UNR for (int m = 0; m < 4; ++m) { aR[m] = (f32x4){0,0,0,0}; aZ[m] = aR[m]; aN[m] = aR[m]; }
      #pragma unroll 2
      for (int kt = 0; kt < 8; ++kt) {
        const int k0 = kt * 32 + lg * 8;
        f16x8 Br = *(const f16x8*)(p0base + k0);
        f16x8 Bz = *(const f16x8*)(p0base + 65536 + k0);
        f16x8 Bn = *(const f16x8*)(p0base + 131072 + k0);
        UNR for (int m = 0; m < 4; ++m) {
          f16x8 A = *(const f16x8*)&hall[h0r + (m >> 1) * SLOT_ + lswz((m & 1) * 16 + l15, k0)];
          aR[m] = MFMA16(A, Br, aR[m]);
          aZ[m] = MFMA16(A, Bz, aZ[m]);
          aN[m] = MFMA16(A, Bn, aN[m]);
        }
      }
      if (tau >= 0) {
        UNR for (int m = 0; m < 4; ++m) {
          const unsigned hsel = (m < 2) ? lo32 : hi32;
          UNR for (int e = 0; e < 4; ++e) {
            const int lrow = (m & 1) * 16 + lg4 + e;
            float fb = (float)((hsel >> ((m & 1) * 16 + lg4 + e)) & 1u);
            float giR = fmaf(fb, dR, sumR0);
            float giZ = fmaf(fb, dZ, sumZ0);
            float giN = fmaf(fb, dN, sumN0);
            float r  = sigm(aR[m][e] + giR);
            float z  = sigm(aZ[m][e] + giZ);
            float n  = tanh_fast(giN + r * (aN[m][e] + bhh0n_c));
            float hn = (1.0f - z) * n + z * (float)h0p[m][e];
            h0p[m][e] = (f16)hn;
            hall[h0w + (m >> 1) * SLOT_ + lswz(lrow, col)] = h0p[m][e];
          }
        }
      } else {
        UNR for (int m = 0; m < 4; ++m) {
          UNR for (int e = 0; e < 4; ++e) {
            const int lrow = (m & 1) * 16 + lg4 + e;
            float r  = sigm(aR[m][e] + baseR);
            float z  = sigm(aZ[m][e] + baseZ);
            float n  = tanh_fast(baseN + r * (aN[m][e] + bhh0n_c));
            float hn = (1.0f - z) * n;           // h0_old = 0
            h0p[m][e] = (f16)hn;
            hall[h0w + (m >> 1) * SLOT_ + lswz(lrow, col)] = h0p[m][e];
          }
        }
      }
    }

    // ================= head(tau-2): reads h1'(tau-2) in h1r =================
    if (tau >= 2) {
      const int t = tau - 2;
      float d0 = 0.f, d1 = 0.f;
      #pragma unroll
      for (int j = 0; j < 2; ++j) {
        const int k0 = t16 * 16 + j * 8;
        f16x8 hv = *(const f16x8*)&hall[h1r + (hrow >> 5) * SLOT_ + lswz(hrow & 31, k0)];
        f32x4 w0a = *(const f32x4*)&wampL[k0];
        f32x4 w0b = *(const f32x4*)&wampL[k0 + 4];
        f32x4 w1a = *(const f32x4*)&wampL[256 + k0];
        f32x4 w1b = *(const f32x4*)&wampL[256 + k0 + 4];
        #pragma unroll
        for (int i = 0; i < 4; ++i) {
          float hfa = (float)hv[i], hfb = (float)hv[4 + i];
          d0 = fmaf(hfa, w0a[i], d0); d0 = fmaf(hfb, w0b[i], d0);
          d1 = fmaf(hfa, w1a[i], d1); d1 = fmaf(hfb, w1b[i], d1);
        }
      }
      d0 += __shfl_xor(d0, 1); d0 += __shfl_xor(d0, 2);
      d0 += __shfl_xor(d0, 4); d0 += __shfl_xor(d0, 8);
      d1 += __shfl_xor(d1, 1); d1 += __shfl_xor(d1, 2);
      d1 += __shfl_xor(d1, 4); d1 += __shfl_xor(d1, 8);
      const int bit = (unsigned)(hmk >> t) & 1u;
      float diff = (d0 + ba0) - (d1 + ba1);
      if (bit) diff = -diff;
      prob *= __builtin_amdgcn_rcpf(1.0f + __builtin_amdgcn_exp2f(diff * -1.442695040888963f));
    }
    __syncthreads();
  }

  // final head: t = 63; h1'(63) written at iter 64 to slot (64&1)=0
  {
    const int hb = 4 * SLOT_;
    float d0 = 0.f, d1 = 0.f;
    #pragma unroll
    for (int j = 0; j < 2; ++j) {
      const int k0 = t16 * 16 + j * 8;
      f16x8 hv = *(const f16x8*)&hall[hb + (hrow >> 5) * SLOT_ + lswz(hrow & 31, k0)];
      f32x4 w0a = *(const f32x4*)&wampL[k0];
      f32x4 w0b = *(const f32x4*)&wampL[k0 + 4];
      f32x4 w1a = *(const f32x4*)&wampL[256 + k0];
      f32x4 w1b = *(const f32x4*)&wampL[256 + k0 + 4];
      #pragma unroll
      for (int i = 0; i < 4; ++i) {
        float hfa = (float)hv[i], hfb = (float)hv[4 + i];
        d0 = fmaf(hfa, w0a[i], d0); d0 = fmaf(hfb, w0b[i], d0);
        d1 = fmaf(hfa, w1a[i], d1); d1 = fmaf(hfb, w1b[i], d1);
      }
    }
    d0 += __shfl_xor(d0, 1); d0 += __shfl_xor(d0, 2);
    d0 += __shfl_xor(d0, 4); d0 += __shfl_xor(d0, 8);
    d1 += __shfl_xor(d1, 1); d1 += __shfl_xor(d1, 2);
    d1 += __shfl_xor(d1, 4); d1 += __shfl_xor(d1, 8);
    const int bit = (unsigned)(hmk >> 63) & 1u;
    float diff = (d0 + ba0) - (d1 + ba1);
    if (bit) diff = -diff;
    prob *= __builtin_amdgcn_rcpf(1.0f + __builtin_amdgcn_exp2f(diff * -1.442695040888963f));
  }

  if (t16 == 0) out[rowbase + hrow] = sqrtf(prob);
}

extern "C" void kernel_launch(void* const* d_in, const int* in_sizes, int n_in,
                              void* d_out, int out_size, void* d_ws, size_t ws_size,
                              hipStream_t stream) {
  const int*   x     = (const int*)d_in[0];
  const float* w_ih0 = (const float*)d_in[1];
  const float* w_hh0 = (const float*)d_in[2];
  const float* b_ih0 = (const float*)d_in[3];
  const float* b_hh0 = (const float*)d_in[4];
  const float* w_ih1 = (const float*)d_in[5];
  const float* w_hh1 = (const float*)d_in[6];
  const float* b_ih1 = (const float*)d_in[7];
  const float* b_hh1 = (const float*)d_in[8];
  const float* w_amp = (const float*)d_in[9];
  const float* b_amp = (const float*)d_in[10];
  (void)in_sizes; (void)n_in; (void)out_size; (void)ws_size;

  f16* W16 = (f16*)d_ws;   // 3*768*256*2 = 1.18 MB of workspace
  hipLaunchKernelGGL(wcvt, dim3(768), dim3(256), 0, stream, w_hh0, w_ih1, w_hh1, W16);
  hipLaunchKernelGGL(rnnwf, dim3(32768 / TB_), dim3(NT_), 0, stream,
                     x, w_ih0, b_ih0, b_hh0, b_ih1, b_hh1, w_amp, b_amp, W16,
                     (float*)d_out);
}

// Round 16
// 4960.872 us; speedup vs baseline: 1.5663x; 1.1459x over previous
//
#include <hip/hip_runtime.h>

typedef _Float16 f16;
typedef _Float16 f16x8 __attribute__((ext_vector_type(8)));
typedef float f32x4 __attribute__((ext_vector_type(4)));

#define H_    256
#define TB_   64      // batch rows per workgroup
#define NT_   1024    // 16 waves, 4 per SIMD
#define SORB_ 64
#define SLOT_ 8192    // 32 rows * 256 cols f16 = 16 KB; a pair (64 rows) = 2 slots

#define MFMA16(a, b, c) __builtin_amdgcn_mfma_f32_16x16x32_f16((a), (b), (c), 0, 0, 0)
#define UNR _Pragma("unroll")

// fast activations: native v_exp_f32 (computes 2^x) + v_rcp_f32; rel err ~1e-7,
// negligible vs the f16-weight quantization (~1e-3 budget)
__device__ __forceinline__ float sigm(float v) {
  return __builtin_amdgcn_rcpf(1.0f + __builtin_amdgcn_exp2f(v * -1.442695040888963f));
}
__device__ __forceinline__ float tanh_fast(float v) {
  float a = fabsf(v);
  float e = __builtin_amdgcn_exp2f(a * -2.885390081777927f);
  float t = (1.0f - e) * __builtin_amdgcn_rcpf(1.0f + e);
  return copysignf(t, v);
}
// XOR-swizzle within a 32-row slot (f16 units, 16B granule)
__device__ __forceinline__ int lswz(int lrow, int col) {
  return lrow * H_ + (col ^ ((lrow & 7) << 3));
}

// fp32 -> f16 weight conversion: [whh0 | wih1 | whh1], each [768][256] row-major
__global__ void wcvt(const float* __restrict__ a, const float* __restrict__ b,
                     const float* __restrict__ c, f16* __restrict__ o) {
  int i = blockIdx.x * 256 + threadIdx.x;
  const int n = 768 * 256;
  if (i < n) {
    o[i]         = (f16)a[i];
    o[n + i]     = (f16)b[i];
    o[2 * n + i] = (f16)c[i];
  }
}

__global__ __launch_bounds__(NT_, 4) void rnnwf(
    const int* __restrict__ x,
    const float* __restrict__ w_ih0, const float* __restrict__ b_ih0,
    const float* __restrict__ b_hh0, const float* __restrict__ b_ih1,
    const float* __restrict__ b_hh1, const float* __restrict__ w_amp,
    const float* __restrict__ b_amp, const f16* __restrict__ W16,
    float* __restrict__ out)
{
  __shared__ __align__(16) f16 hall[6 * SLOT_];  // 96 KB: 3 pairs of 64 rows
  __shared__ float wampL[512];
  __shared__ unsigned short bitsL[TB_ * 4];
  __shared__ unsigned long long bitsT[SORB_];    // bit r of bitsT[t] = x[row r][t]

  const int tid  = threadIdx.x;
  const int wave = tid >> 6;                  // 0..15
  const int lane = tid & 63;
  const int l15  = lane & 15;
  const int lg   = lane >> 4;                 // 0..3
  const int lg4  = lg << 2;
  const int col  = wave * 16 + l15;           // fixed hidden column per thread
  const int rowbase = blockIdx.x * TB_;

  // ---- one-time setup ----
  for (int j = tid; j < 512; j += NT_) wampL[j] = w_amp[j];
  if (tid < 256) {
    int row = tid >> 2, q = tid & 3;
    const int* xp = x + (size_t)(rowbase + row) * SORB_ + q * 16;
    unsigned m = 0;
    #pragma unroll
    for (int i = 0; i < 16; ++i) m |= (unsigned)(xp[i] & 1) << i;
    bitsL[row * 4 + q] = (unsigned short)m;
  }
  for (int i = tid; i < 6 * SLOT_; i += NT_) hall[i] = (f16)0.f;

  // per-thread L0 gate tables (step-invariant, register-resident)
  const float baseR = b_ih0[col]       + b_hh0[col];
  const float baseZ = b_ih0[256 + col] + b_hh0[256 + col];
  const float baseN = b_ih0[512 + col];
  const float wR0 = w_ih0[2 * col + 0],         wR1 = w_ih0[2 * col + 1];
  const float wZ0 = w_ih0[2 * (256 + col) + 0], wZ1 = w_ih0[2 * (256 + col) + 1];
  const float wN0 = w_ih0[2 * (512 + col) + 0], wN1 = w_ih0[2 * (512 + col) + 1];
  const float sumR0 = baseR + wR0, dR = wR1 - wR0;
  const float sumZ0 = baseZ + wZ0, dZ = wZ1 - wZ0;
  const float sumN0 = baseN + wN0, dN = wN1 - wN0;
  const float bhh0n_c = b_hh0[512 + col];
  const float b1r_c   = b_ih1[col]       + b_hh1[col];
  const float b1z_c   = b_ih1[256 + col] + b_hh1[256 + col];
  const float b1ni_c  = b_ih1[512 + col];
  const float b1nh_c  = b_hh1[512 + col];
  const float ba0 = b_amp[0], ba1 = b_amp[1];
  __syncthreads();

  // transpose bit matrix: bitsT[t] holds bit-per-row for step t (broadcast read later)
  if (tid < SORB_) {
    unsigned long long mk = 0ull;
    const int q = tid >> 4, sh = tid & 15;
    #pragma unroll 4
    for (int r = 0; r < TB_; ++r)
      mk |= (unsigned long long)((bitsL[r * 4 + q] >> sh) & 1) << r;
    bitsT[tid] = mk;
  }
  __syncthreads();

  float prob = 1.0f;
  const f16* Wih1 = W16 + 768 * 256;
  const f16* Whh1 = W16 + 2 * 768 * 256;
  const f16* p0base = W16  + col * 256;
  const f16* pibase = Wih1 + col * 256;
  const f16* phbase = Whh1 + col * 256;

  // head constants
  const int hrow = tid >> 4;            // 0..63
  const int t16  = tid & 15;
  const int hsh  = hrow & 31;
  const bool hhi = hrow >= 32;

  int pa = 0, pb = 2 * SLOT_, pc = 4 * SLOT_;   // h0_cur, h1_cur, free

  for (int t = -1; t < SORB_; ++t) {
    unsigned lo32 = 0u, hi32 = 0u;
    if (t >= 0) {
      unsigned long long mk = bitsT[t];        // uniform address -> broadcast
      lo32 = (unsigned)mk; hi32 = (unsigned)(mk >> 32);
    }

    // ================= layer 0: read pa -> write pc =================
    {
      f32x4 aR[4], aZ[4], aN[4];
      UNR for (int m = 0; m < 4; ++m) { aR[m] = (f32x4){0,0,0,0}; aZ[m] = aR[m]; aN[m] = aR[m]; }
      #pragma unroll 2
      for (int kt = 0; kt < 8; ++kt) {
        const int k0 = kt * 32 + lg * 8;
        f16x8 Br = *(const f16x8*)(p0base + k0);
        f16x8 Bz = *(const f16x8*)(p0base + 65536 + k0);
        f16x8 Bn = *(const f16x8*)(p0base + 131072 + k0);
        UNR for (int m = 0; m < 4; ++m) {
          f16x8 A = *(const f16x8*)&hall[pa + (m >> 1) * SLOT_ + lswz((m & 1) * 16 + l15, k0)];
          aR[m] = MFMA16(A, Br, aR[m]);
          aZ[m] = MFMA16(A, Bz, aZ[m]);
          aN[m] = MFMA16(A, Bn, aN[m]);
        }
      }
      if (t >= 0) {
        UNR for (int m = 0; m < 4; ++m) {
          const unsigned hsel = (m < 2) ? lo32 : hi32;
          UNR for (int e = 0; e < 4; ++e) {
            const int lrow = (m & 1) * 16 + lg4 + e;
            float fb = (float)((hsel >> ((m & 1) * 16 + lg4 + e)) & 1u);
            float giR = fmaf(fb, dR, sumR0);
            float giZ = fmaf(fb, dZ, sumZ0);
            float giN = fmaf(fb, dN, sumN0);
            float r  = sigm(aR[m][e] + giR);
            float z  = sigm(aZ[m][e] + giZ);
            float n  = tanh_fast(giN + r * (aN[m][e] + bhh0n_c));
            float ho = (float)hall[pa + (m >> 1) * SLOT_ + lswz(lrow, col)];
            hall[pc + (m >> 1) * SLOT_ + lswz(lrow, col)] = (f16)((1.0f - z) * n + z * ho);
          }
        }
      } else {
        UNR for (int m = 0; m < 4; ++m) {
          UNR for (int e = 0; e < 4; ++e) {
            const int lrow = (m & 1) * 16 + lg4 + e;
            float r  = sigm(aR[m][e] + baseR);
            float z  = sigm(aZ[m][e] + baseZ);
            float n  = tanh_fast(baseN + r * (aN[m][e] + bhh0n_c));
            float ho = (float)hall[pa + (m >> 1) * SLOT_ + lswz(lrow, col)];
            hall[pc + (m >> 1) * SLOT_ + lswz(lrow, col)] = (f16)((1.0f - z) * n + z * ho);
          }
        }
      }
    }
    __syncthreads();

    // ===== layer 1: read pc (h0') + pb (h1) -> write pa =====
    // MERGED: one kt loop, all four gate accumulator sets (64 accs -> AGPR file),
    // B loaded once per kt, A0/A1 each read once per kt (64 ds_read_b128 vs 128),
    // element-wise epilogue (no rv/zv arrays -> no arch-side spill).
    // Per-accumulator contribution order identical to the 2-pass version
    // (A0 before A1 within each kt, kt ascending) -> bitwise-identical output.
    {
      f32x4 tR[4], tZ[4], tNi[4], tNh[4];
      UNR for (int m = 0; m < 4; ++m) {
        tR[m] = (f32x4){0,0,0,0}; tZ[m] = tR[m]; tNi[m] = tR[m]; tNh[m] = tR[m];
      }
      #pragma unroll 1
      for (int kt = 0; kt < 8; ++kt) {
        const int k0 = kt * 32 + lg * 8;
        {  // ih source: 3 B streams live, A0 loaded per-m
          f16x8 BiR = *(const f16x8*)(pibase + k0);
          f16x8 BiZ = *(const f16x8*)(pibase + 65536 + k0);
          f16x8 BiN = *(const f16x8*)(pibase + 131072 + k0);
          UNR for (int m = 0; m < 4; ++m) {
            f16x8 A0 = *(const f16x8*)&hall[pc + (m >> 1) * SLOT_ + lswz((m & 1) * 16 + l15, k0)];
            tR[m]  = MFMA16(A0, BiR, tR[m]);
            tZ[m]  = MFMA16(A0, BiZ, tZ[m]);
            tNi[m] = MFMA16(A0, BiN, tNi[m]);
          }
        }
        {  // hh source
          f16x8 BhR = *(const f16x8*)(phbase + k0);
          f16x8 BhZ = *(const f16x8*)(phbase + 65536 + k0);
          f16x8 BhN = *(const f16x8*)(phbase + 131072 + k0);
          UNR for (int m = 0; m < 4; ++m) {
            f16x8 A1 = *(const f16x8*)&hall[pb + (m >> 1) * SLOT_ + lswz((m & 1) * 16 + l15, k0)];
            tR[m]  = MFMA16(A1, BhR, tR[m]);
            tZ[m]  = MFMA16(A1, BhZ, tZ[m]);
            tNh[m] = MFMA16(A1, BhN, tNh[m]);
          }
        }
      }
      UNR for (int m = 0; m < 4; ++m) {
        UNR for (int e = 0; e < 4; ++e) {
          const int lrow = (m & 1) * 16 + lg4 + e;
          float r  = sigm(tR[m][e] + b1r_c);
          float z  = sigm(tZ[m][e] + b1z_c);
          float n  = tanh_fast(tNi[m][e] + b1ni_c + r * (tNh[m][e] + b1nh_c));
          float ho = (float)hall[pb + (m >> 1) * SLOT_ + lswz(lrow, col)];
          hall[pa + (m >> 1) * SLOT_ + lswz(lrow, col)] = (f16)((1.0f - z) * n + z * ho);
        }
      }
    }
    __syncthreads();

    // ================= amplitude head (reads pa = h1_new) =================
    if (t >= 0) {
      float d0 = 0.f, d1 = 0.f;
      #pragma unroll
      for (int j = 0; j < 2; ++j) {
        const int k0 = t16 * 16 + j * 8;
        f16x8 hv = *(const f16x8*)&hall[pa + (hrow >> 5) * SLOT_ + lswz(hrow & 31, k0)];
        f32x4 w0a = *(const f32x4*)&wampL[k0];
        f32x4 w0b = *(const f32x4*)&wampL[k0 + 4];
        f32x4 w1a = *(const f32x4*)&wampL[256 + k0];
        f32x4 w1b = *(const f32x4*)&wampL[256 + k0 + 4];
        #pragma unroll
        for (int i = 0; i < 4; ++i) {
          float hfa = (float)hv[i], hfb = (float)hv[4 + i];
          d0 = fmaf(hfa, w0a[i], d0); d0 = fmaf(hfb, w0b[i], d0);
          d1 = fmaf(hfa, w1a[i], d1); d1 = fmaf(hfb, w1b[i], d1);
        }
      }
      d0 += __shfl_xor(d0, 1); d0 += __shfl_xor(d0, 2);
      d0 += __shfl_xor(d0, 4); d0 += __shfl_xor(d0, 8);
      d1 += __shfl_xor(d1, 1); d1 += __shfl_xor(d1, 2);
      d1 += __shfl_xor(d1, 4); d1 += __shfl_xor(d1, 8);
      const unsigned hm = hhi ? hi32 : lo32;
      const int bit = (hm >> hsh) & 1;
      float diff = (d0 + ba0) - (d1 + ba1);
      if (bit) diff = -diff;
      prob *= __builtin_amdgcn_rcpf(1.0f + __builtin_amdgcn_exp2f(diff * -1.442695040888963f));
    }

    // rotate pairs: h0_cur := pc, h1_cur := pa, free := pb
    int tmp = pa; pa = pc; pc = pb; pb = tmp;
  }

  if (t16 == 0) out[rowbase + hrow] = sqrtf(prob);
}

extern "C" void kernel_launch(void* const* d_in, const int* in_sizes, int n_in,
                              void* d_out, int out_size, void* d_ws, size_t ws_size,
                              hipStream_t stream) {
  const int*   x     = (const int*)d_in[0];
  const float* w_ih0 = (const float*)d_in[1];
  const float* w_hh0 = (const float*)d_in[2];
  const float* b_ih0 = (const float*)d_in[3];
  const float* b_hh0 = (const float*)d_in[4];
  const float* w_ih1 = (const float*)d_in[5];
  const float* w_hh1 = (const float*)d_in[6];
  const float* b_ih1 = (const float*)d_in[7];
  const float* b_hh1 = (const float*)d_in[8];
  const float* w_amp = (const float*)d_in[9];
  const float* b_amp = (const float*)d_in[10];
  (void)in_sizes; (void)n_in; (void)out_size; (void)ws_size;

  f16* W16 = (f16*)d_ws;   // 3*768*256*2 = 1.18 MB of workspace
  hipLaunchKernelGGL(wcvt, dim3(768), dim3(256), 0, stream, w_hh0, w_ih1, w_hh1, W16);
  hipLaunchKernelGGL(rnnwf, dim3(32768 / TB_), dim3(NT_), 0, stream,
                     x, w_ih0, b_ih0, b_hh0, b_ih1, b_hh1, w_amp, b_amp, W16,
                     (float*)d_out);
}